// Round 9
// baseline (146.867 us; speedup 1.0000x reference)
//
#include <hip/hip_runtime.h>

#define N_ENT 400000
#define N_REL 500
#define N_TS 365
#define RANK 64
#define BATCH 256

typedef __attribute__((ext_vector_type(8))) __bf16 bf16x8;
typedef __attribute__((ext_vector_type(16))) float f32x16;
typedef __attribute__((ext_vector_type(4))) float f32x4;

// ---------------------------------------------------------------------------
// Kernel 1: fused prep + tail.  Grid = 365 blocks x 64 threads.
// ---------------------------------------------------------------------------
__global__ void prep_tail_kernel(const float* __restrict__ E0,
                                 const float* __restrict__ E1,
                                 const float* __restrict__ E2,
                                 const float* __restrict__ E3,
                                 const float* __restrict__ E4,
                                 const int* __restrict__ x,
                                 __bf16* __restrict__ Vbf,  // [BATCH][RANK]
                                 float* __restrict__ bias,  // [BATCH]
                                 float* __restrict__ out)
{
    const int b = blockIdx.x;
    const int k = threadIdx.x;

    const long long SCORES = (long long)BATCH * N_ENT;  // 102,400,000
    const int CP = (N_TS - 1) * RANK;                   // 23,296

    if (b == 364 && k == 0) out[SCORES] = 0.0f;  // cl_loss
    if (b < N_TS - 1) {
        const int idx = b * RANK + k;
        out[SCORES + 1 + 0LL * CP + idx] = E2[idx];
        out[SCORES + 1 + 1LL * CP + idx] = E3[idx];
        out[SCORES + 1 + 2LL * CP + idx] = E4[idx];
    }

    if (b < BATCH) {
        const int i = b;
        const int i0 = x[i * 4 + 0];
        const int i1 = x[i * 4 + 1];
        const int i3 = x[i * 4 + 3];

        const float lhs = E0[i0 * RANK + k];
        const float rel = E1[i1 * RANK + k];
        const float te  = E2[i3 * RANK + k];
        const float tr  = E3[i3 * RANK + k];

        // complex_mul(rel, comp_time) with half-width 32
        const int  kh = k & 31;
        const float a = E1[i1 * RANK + kh];
        const float bb = E1[i1 * RANK + 32 + kh];
        const float c = E4[i3 * RANK + kh];
        const float d = E4[i3 * RANK + 32 + kh];
        const float cm = (k < 32) ? (a * c + bb * d) : (a * d - bb * c);
        const float rel_ = rel + cm;

        const float v = 2.0f * (lhs * rel_ - te * tr);
        Vbf[i * RANK + k] = (__bf16)v;

        float rb = 2.0f * te * (lhs * tr + te * rel_);
        #pragma unroll
        for (int off = 32; off > 0; off >>= 1)
            rb += __shfl_down(rb, off, 64);
        if (k == 0) bias[i] = rb;
    }
}

// ---------------------------------------------------------------------------
// Kernel 2: scores = V @ E0^T + bias via mfma_f32_32x32x16_bf16.
//   FINE-GRAINED GRID to kill the scheduling drain tail: block = 128 cols x
//   64 rows (2 M-tiles).  Grid = 3125 slabs x 4 row-groups = 12500 blocks
//   (~12 occupancy rounds; drain tail ~ half a block runtime, vs 27 us at
//   grid=1563/1.5 rounds).  Consecutive blockIdx share a column slab ->
//   E0 re-reads (x4 logical) are L2/L3-served.
//   Per M-tile: 4 MFMAs -> LDS ping-pong transpose (1 barrier) -> f32x4
//   row stores, 512 B contiguous per row per block (R5-proven pattern).
//   C layout (verified): col=lane&31, row=(reg&3)+8*(reg>>2)+4*(lane>>5).
// ---------------------------------------------------------------------------
__global__ __launch_bounds__(256) void scores_mfma(
    const float* __restrict__ E0,
    const __bf16* __restrict__ Vbf,
    const float* __restrict__ bias,
    float* __restrict__ out)
{
    __shared__ __align__(16) float tile[2][32][128];  // 32 KiB ping-pong
    __shared__ float sb[64];                          // this block's 64 bias rows

    const int t    = threadIdx.x;
    const int lane = t & 63;
    const int wid  = t >> 6;             // 0..3
    const int l31  = lane & 31;
    const int h    = lane >> 5;          // 0/1
    const int khalf = h * 8;

    const int slab = blockIdx.x >> 2;    // 0..3124  (128-col slab)
    const int rg   = blockIdx.x & 3;     // 0..3     (64-row group)
    const int colbase = slab * 128;
    const int col  = colbase + wid * 32 + l31;
    const int rowbase = rg * 64;

    if (t < 64) sb[t] = bias[rowbase + t];

    // ---- B fragments: 4 x (K=16) over K=64, fp32 -> bf16 in-register ----
    bf16x8 bfrag[4];
    const float* erow = E0 + (size_t)col * RANK;
    #pragma unroll
    for (int f = 0; f < 4; ++f) {
        const int kb = f * 16 + khalf;
        const float4 u0 = *reinterpret_cast<const float4*>(erow + kb);
        const float4 u1 = *reinterpret_cast<const float4*>(erow + kb + 4);
        bfrag[f][0] = (__bf16)u0.x;  bfrag[f][1] = (__bf16)u0.y;
        bfrag[f][2] = (__bf16)u0.z;  bfrag[f][3] = (__bf16)u0.w;
        bfrag[f][4] = (__bf16)u1.x;  bfrag[f][5] = (__bf16)u1.y;
        bfrag[f][6] = (__bf16)u1.z;  bfrag[f][7] = (__bf16)u1.w;
    }

    int p = 0;
    #pragma unroll 1
    for (int mt = 0; mt < 2; ++mt) {
        const __bf16* arow =
            Vbf + (size_t)(rowbase + mt * 32 + l31) * RANK + khalf;

        f32x16 acc;
        #pragma unroll
        for (int j = 0; j < 16; ++j) acc[j] = 0.0f;

        #pragma unroll
        for (int f = 0; f < 4; ++f) {
            const bf16x8 afrag = *reinterpret_cast<const bf16x8*>(arow + f * 16);
            acc = __builtin_amdgcn_mfma_f32_32x32x16_bf16(afrag, bfrag[f], acc, 0, 0, 0);
        }

        // ---- write phase: scatter acc into row-major LDS tile ----
        #pragma unroll
        for (int j = 0; j < 16; ++j) {
            const int row = (j & 3) + 8 * (j >> 2) + 4 * h;
            tile[p][row][wid * 32 + l31] = acc[j];
        }
        __syncthreads();

        // ---- read phase: row-major f32x4 stores, bias folded in ----
        #pragma unroll
        for (int q = 0; q < 4; ++q) {
            const int row = q * 8 + (t >> 5);          // 0..31
            const int mloc = mt * 32 + row;            // 0..63 within block
            f32x4 v = *reinterpret_cast<const f32x4*>(&tile[p][row][(t & 31) * 4]);
            const float bv = sb[mloc];
            v.x += bv; v.y += bv; v.z += bv; v.w += bv;
            *reinterpret_cast<f32x4*>(
                &out[(size_t)(rowbase + mloc) * N_ENT + colbase + (t & 31) * 4]) = v;
        }
        p ^= 1;
        // single barrier per mt: next iteration writes the other buffer;
        // this buffer is reused only after the next barrier (hazard-checked).
    }
}

// ---------------------------------------------------------------------------
extern "C" void kernel_launch(void* const* d_in, const int* in_sizes, int n_in,
                              void* d_out, int out_size, void* d_ws, size_t ws_size,
                              hipStream_t stream) {
    const float* E0 = (const float*)d_in[0];
    const float* E1 = (const float*)d_in[1];
    const float* E2 = (const float*)d_in[2];
    const float* E3 = (const float*)d_in[3];
    const float* E4 = (const float*)d_in[4];
    const int*   x  = (const int*)d_in[5];

    float* out = (float*)d_out;

    float*  bias = (float*)d_ws;                    // 1 KiB
    __bf16* Vbf  = (__bf16*)((char*)d_ws + 1024);   // 32 KiB

    prep_tail_kernel<<<N_TS, RANK, 0, stream>>>(E0, E1, E2, E3, E4, x, Vbf, bias, out);

    const int nblk = (N_ENT / 128) * 4;  // 3125 slabs x 4 row-groups = 12500
    scores_mfma<<<nblk, 256, 0, stream>>>(E0, Vbf, bias, out);
}

// Round 10
// 97.486 us; speedup vs baseline: 1.5065x; 1.5065x over previous
//
#include <hip/hip_runtime.h>

#define N_ENT 400000
#define N_REL 500
#define N_TS 365
#define RANK 64
#define BATCH 256

typedef __attribute__((ext_vector_type(8))) __bf16 bf16x8;
typedef __attribute__((ext_vector_type(16))) float f32x16;
typedef __attribute__((ext_vector_type(4))) float f32x4;

// ---------------------------------------------------------------------------
// Kernel 1: fused prep + tail.  Grid = 365 blocks x 64 threads.
//   blocks 0..255 : batch prep -> Vbf (bf16) + bias
//   blocks 0..363 : copy row b of E2/E3/E4 into the tail outputs
//   block 364     : cl_loss = 0
// ---------------------------------------------------------------------------
__global__ void prep_tail_kernel(const float* __restrict__ E0,
                                 const float* __restrict__ E1,
                                 const float* __restrict__ E2,
                                 const float* __restrict__ E3,
                                 const float* __restrict__ E4,
                                 const int* __restrict__ x,
                                 __bf16* __restrict__ Vbf,  // [BATCH][RANK]
                                 float* __restrict__ bias,  // [BATCH]
                                 float* __restrict__ out)
{
    const int b = blockIdx.x;
    const int k = threadIdx.x;

    const long long SCORES = (long long)BATCH * N_ENT;  // 102,400,000
    const int CP = (N_TS - 1) * RANK;                   // 23,296

    if (b == 364 && k == 0) out[SCORES] = 0.0f;  // cl_loss
    if (b < N_TS - 1) {
        const int idx = b * RANK + k;
        out[SCORES + 1 + 0LL * CP + idx] = E2[idx];
        out[SCORES + 1 + 1LL * CP + idx] = E3[idx];
        out[SCORES + 1 + 2LL * CP + idx] = E4[idx];
    }

    if (b < BATCH) {
        const int i = b;
        const int i0 = x[i * 4 + 0];
        const int i1 = x[i * 4 + 1];
        const int i3 = x[i * 4 + 3];

        const float lhs = E0[i0 * RANK + k];
        const float rel = E1[i1 * RANK + k];
        const float te  = E2[i3 * RANK + k];
        const float tr  = E3[i3 * RANK + k];

        // complex_mul(rel, comp_time) with half-width 32
        const int  kh = k & 31;
        const float a = E1[i1 * RANK + kh];
        const float bb = E1[i1 * RANK + 32 + kh];
        const float c = E4[i3 * RANK + kh];
        const float d = E4[i3 * RANK + 32 + kh];
        const float cm = (k < 32) ? (a * c + bb * d) : (a * d - bb * c);
        const float rel_ = rel + cm;

        const float v = 2.0f * (lhs * rel_ - te * tr);
        Vbf[i * RANK + k] = (__bf16)v;

        float rb = 2.0f * te * (lhs * tr + te * rel_);
        #pragma unroll
        for (int off = 32; off > 0; off >>= 1)
            rb += __shfl_down(rb, off, 64);
        if (k == 0) bias[i] = rb;
    }
}

// ---------------------------------------------------------------------------
// Kernel 2: scores = V @ E0^T + bias via mfma_f32_32x32x16_bf16.
//   Identical to the round-5 120.0 us version EXCEPT the final output stores
//   are non-temporal: the 410 MB write stream is touch-once, so skipping
//   L2/L3 allocation keeps E0 (102 MB) L3-resident across graph replays
//   (round-1 FETCH showed ~half of E0 refetched per replay = write churn).
//   Loads stay cached (R4 showed NT loads regress).
//   C layout (verified): col=lane&31, row=(reg&3)+8*(reg>>2)+4*(lane>>5).
// ---------------------------------------------------------------------------
__global__ __launch_bounds__(256) void scores_mfma(
    const float* __restrict__ E0,
    const __bf16* __restrict__ Vbf,
    const float* __restrict__ bias,
    float* __restrict__ out)
{
    __shared__ __align__(16) float tile[2][32][128];  // 32 KiB ping-pong
    __shared__ float sbias[BATCH];                    // 1 KiB

    const int t    = threadIdx.x;
    const int lane = t & 63;
    const int wid  = t >> 6;             // 0..3
    const int l31  = lane & 31;
    const int h    = lane >> 5;          // 0/1
    const int colbase = blockIdx.x * 128;
    const int col  = colbase + wid * 32 + l31;
    const int khalf = h * 8;

    sbias[t] = bias[t];

    // ---- B fragments: 4 x (K=16) over K=64, fp32 -> bf16 in-register ----
    bf16x8 bfrag[4];
    const float* erow = E0 + (size_t)col * RANK;
    #pragma unroll
    for (int f = 0; f < 4; ++f) {
        const int kb = f * 16 + khalf;
        const float4 u0 = *reinterpret_cast<const float4*>(erow + kb);
        const float4 u1 = *reinterpret_cast<const float4*>(erow + kb + 4);
        bfrag[f][0] = (__bf16)u0.x;  bfrag[f][1] = (__bf16)u0.y;
        bfrag[f][2] = (__bf16)u0.z;  bfrag[f][3] = (__bf16)u0.w;
        bfrag[f][4] = (__bf16)u1.x;  bfrag[f][5] = (__bf16)u1.y;
        bfrag[f][6] = (__bf16)u1.z;  bfrag[f][7] = (__bf16)u1.w;
    }

    int p = 0;
    #pragma unroll 1
    for (int mt = 0; mt < 8; ++mt) {
        const __bf16* arow = Vbf + (size_t)(mt * 32 + l31) * RANK + khalf;

        f32x16 acc;
        #pragma unroll
        for (int j = 0; j < 16; ++j) acc[j] = 0.0f;

        #pragma unroll
        for (int f = 0; f < 4; ++f) {
            const bf16x8 afrag = *reinterpret_cast<const bf16x8*>(arow + f * 16);
            acc = __builtin_amdgcn_mfma_f32_32x32x16_bf16(afrag, bfrag[f], acc, 0, 0, 0);
        }

        // ---- write phase: scatter acc into row-major LDS tile ----
        #pragma unroll
        for (int j = 0; j < 16; ++j) {
            const int row = (j & 3) + 8 * (j >> 2) + 4 * h;
            tile[p][row][wid * 32 + l31] = acc[j];
        }
        __syncthreads();

        // ---- read phase: row-major f32x4 NT stores, bias folded in ----
        const int m0 = mt * 32;
        #pragma unroll
        for (int q = 0; q < 4; ++q) {
            const int row = q * 8 + (t >> 5);
            f32x4 v = *reinterpret_cast<const f32x4*>(&tile[p][row][(t & 31) * 4]);
            const float bv = sbias[m0 + row];
            v.x += bv; v.y += bv; v.z += bv; v.w += bv;
            __builtin_nontemporal_store(v,
                reinterpret_cast<f32x4*>(
                    &out[(size_t)(m0 + row) * N_ENT + colbase + (t & 31) * 4]));
        }
        p ^= 1;
        // no second barrier: next iteration writes the other buffer; reuse of
        // this buffer happens only after the NEXT barrier (hazard-checked).
    }
}

// ---------------------------------------------------------------------------
extern "C" void kernel_launch(void* const* d_in, const int* in_sizes, int n_in,
                              void* d_out, int out_size, void* d_ws, size_t ws_size,
                              hipStream_t stream) {
    const float* E0 = (const float*)d_in[0];
    const float* E1 = (const float*)d_in[1];
    const float* E2 = (const float*)d_in[2];
    const float* E3 = (const float*)d_in[3];
    const float* E4 = (const float*)d_in[4];
    const int*   x  = (const int*)d_in[5];

    float* out = (float*)d_out;

    float*  bias = (float*)d_ws;                    // 1 KiB
    __bf16* Vbf  = (__bf16*)((char*)d_ws + 1024);   // 32 KiB

    prep_tail_kernel<<<N_TS, RANK, 0, stream>>>(E0, E1, E2, E3, E4, x, Vbf, bias, out);

    const int nblk = N_ENT / 128;  // 3125
    scores_mfma<<<nblk, 256, 0, stream>>>(E0, Vbf, bias, out);
}